// Round 1
// baseline (1099.213 us; speedup 1.0000x reference)
//
#include <hip/hip_runtime.h>
#include <hip/hip_bf16.h>

// Problem constants (fixed by setup_inputs)
constexpr int T_ = 4, B_ = 8, N_ = 1024, C_ = 512, H_ = 8, D_ = 64;
constexpr int M_ = 8192;             // rows per timestep
constexpr int MT_ = 32768;           // T*M
constexpr int K_ = 512;

#define TAU_INV 0.5f
#define V_TH    1.0f
#define BN_EPS  1e-5f

// ---- load 4 consecutive elements as float ---------------------------------
__device__ __forceinline__ void ld4(const float* p, float* d) {
  const float4 v = *(const float4*)p;
  d[0] = v.x; d[1] = v.y; d[2] = v.z; d[3] = v.w;
}
__device__ __forceinline__ void ld4(const __hip_bfloat16* p, float* d) {
  const ushort4 u = *(const ushort4*)p;
  d[0] = __bfloat162float(*(const __hip_bfloat16*)&u.x);
  d[1] = __bfloat162float(*(const __hip_bfloat16*)&u.y);
  d[2] = __bfloat162float(*(const __hip_bfloat16*)&u.z);
  d[3] = __bfloat162float(*(const __hip_bfloat16*)&u.w);
}
// ---- load 8 consecutive bf16 as float -------------------------------------
__device__ __forceinline__ void ld8bf(const __hip_bfloat16* p, float* d) {
  union { uint4 u; ushort s[8]; } q;
  q.u = *(const uint4*)p;
#pragma unroll
  for (int j = 0; j < 8; ++j)
    d[j] = __bfloat162float(*(const __hip_bfloat16*)&q.s[j]);
}
// ---- store 4 consecutive values -------------------------------------------
__device__ __forceinline__ void st4(__hip_bfloat16* p, const float* s) {
  ushort4 u;
  *(__hip_bfloat16*)&u.x = __float2bfloat16(s[0]);
  *(__hip_bfloat16*)&u.y = __float2bfloat16(s[1]);
  *(__hip_bfloat16*)&u.z = __float2bfloat16(s[2]);
  *(__hip_bfloat16*)&u.w = __float2bfloat16(s[3]);
  *(ushort4*)p = u;
}
__device__ __forceinline__ void st4(float* p, const float* s) {
  *(float4*)p = make_float4(s[0], s[1], s[2], s[3]);
}

// ---- async global->LDS, 16B per lane (HW scatters lane*16 from wave base) --
__device__ __forceinline__ void dma16(const void* g, void* l) {
  __builtin_amdgcn_global_load_lds(
      (const __attribute__((address_space(1))) unsigned int*)g,
      (__attribute__((address_space(3))) unsigned int*)l, 16, 0, 0);
}

// ---------------------------------------------------------------------------
// W transpose: Wt[w][k][d] = W[w][d][k]  (k-major rows for DMA staging).
// ---------------------------------------------------------------------------
struct WPtrs { const float* W[4]; };

__global__ __launch_bounds__(256) void transpose_w(WPtrs wp, float* __restrict__ Wt)
{
  __shared__ float tile[32][33];
  const int w = blockIdx.z;
  const float* __restrict__ W = wp.W[w];
  float* __restrict__ dst = Wt + (size_t)w * K_ * C_;
  const int k0 = blockIdx.x * 32, d0 = blockIdx.y * 32;
  const int tx = threadIdx.x, ty = threadIdx.y;   // 32 x 8
#pragma unroll
  for (int i = 0; i < 32; i += 8)
    tile[ty + i][tx] = W[(size_t)(d0 + ty + i) * K_ + k0 + tx];
  __syncthreads();
#pragma unroll
  for (int i = 0; i < 32; i += 8)
    dst[(size_t)(k0 + ty + i) * C_ + d0 + tx] = tile[tx][ty + i];
}

// ---------------------------------------------------------------------------
// x transpose: XT[k][m*4 + t] = x[t][m][k]   (k-major, t-interleaved rows).
// ---------------------------------------------------------------------------
__global__ __launch_bounds__(256) void transpose_x(
    const float* __restrict__ x, float* __restrict__ XT)
{
  __shared__ float tile[32][132];
  const int bk = blockIdx.x * 32, bm = blockIdx.y * 32;
  const int tx = threadIdx.x & 31, ty = threadIdx.x >> 5;   // 32 x 8
#pragma unroll
  for (int t = 0; t < T_; ++t)
#pragma unroll
    for (int i = 0; i < 4; ++i) {
      const int m = ty + 8 * i;
      tile[tx][m * 4 + t] = x[((size_t)t * M_ + bm + m) * K_ + bk + tx];
    }
  __syncthreads();
  const int k = threadIdx.x >> 3, q = threadIdx.x & 7;
#pragma unroll
  for (int u = 0; u < 4; ++u)
    st4(&XT[(size_t)(bk + k) * MT_ + bm * 4 + q * 16 + u * 4],
        &tile[k][q * 16 + u * 4]);
}

// ---------------------------------------------------------------------------
// Fused GEMM (+bias +BN +in-register multi-step LIF) -> spike tensor (T,M,C).
// BIT-EXACTNESS CONTRACT: each output's k-summation is a single fp32
// accumulator over k = 0..511 STRICTLY ASCENDING; bias/BN/LIF expressions are
// textually identical to all prior passing rounds (absmax 0.0). Only data
// MOVEMENT changed (DMA staging, pre-transposed operands).
// ---------------------------------------------------------------------------
template <typename TIn, typename TOut>
struct GArgs {
  const TIn* AT;             // [K][MT] t-interleaved k-major input
  const float* Wt[3];        // [K][C]
  const float* bias[3];
  const float* bn[3];
  TOut* S[3];                // (T, M, C) spikes
};

template <typename TIn, typename TOut>
__global__ __launch_bounds__(256, 2) void gemm_lif(GArgs<TIn, TOut> args)
{
  constexpr int BK = 32;
  constexpr bool BF = (sizeof(TIn) == 2);
  __shared__ __align__(16) TIn  As[BK * 128];
  __shared__ __align__(16) float Bs[BK * 256];

  const int z = blockIdx.z;
  const TIn*   __restrict__ AT   = args.AT;
  const float* __restrict__ Wt   = args.Wt[z];
  const float* __restrict__ bias = args.bias[z];
  const float* __restrict__ bnp  = args.bn[z];
  TOut*        __restrict__ S    = args.S[z];

  const int tid  = threadIdx.x;
  const int lane = tid & 63;
  const int wave = __builtin_amdgcn_readfirstlane(tid >> 6);
  const int tx = tid & 15, ty = tid >> 4;
  const int bm_m = blockIdx.y * 32;       // m-tile base
  const int bm4  = bm_m * 4;              // word base within a k-row of AT
  const int bn0  = blockIdx.x * 256;

  float acc[2][4][4][4];   // [m-grp g][col-grp h][i==t][col j]
#pragma unroll
  for (int g = 0; g < 2; ++g)
#pragma unroll
    for (int h = 0; h < 4; ++h)
#pragma unroll
      for (int i = 0; i < 4; ++i)
#pragma unroll
        for (int j = 0; j < 4; ++j) acc[g][h][i][j] = 0.0f;

  for (int k0 = 0; k0 < K_; k0 += BK) {
    // ---- DMA-stage A tile (BK x 128 elems) -------------------------------
    if constexpr (!BF) {
#pragma unroll
      for (int c = 0; c < 4; ++c) {
        const int ins = wave * 4 + c;                 // 0..15, 2 kk-rows each
        const int kk = ins * 2 + (lane >> 5);
        dma16(AT + (size_t)(k0 + kk) * MT_ + bm4 + (lane & 31) * 4,
              (void*)((float*)As + ins * 256));
      }
    } else {
#pragma unroll
      for (int c = 0; c < 2; ++c) {
        const int ins = wave * 2 + c;                 // 0..7, 4 kk-rows each
        const int kk = ins * 4 + (lane >> 4);
        dma16(AT + (size_t)(k0 + kk) * MT_ + bm4 + (lane & 15) * 8,
              (void*)((TIn*)As + ins * 512));
      }
    }
    // ---- DMA-stage B tile (BK x 256 floats) ------------------------------
#pragma unroll
    for (int c = 0; c < 8; ++c) {
      const int ins = wave * 8 + c;                   // 0..31, 1 kk-row each
      dma16(Wt + (size_t)(k0 + ins) * C_ + bn0 + lane * 4,
            (void*)(Bs + ins * 256));
    }
    __syncthreads();                                  // drains vmcnt

    // ---- hot loop: k strictly ascending ----------------------------------
#pragma unroll
    for (int kk = 0; kk < BK; ++kk) {
      float a[2][4], b[4][4];
#pragma unroll
      for (int g = 0; g < 2; ++g)
        ld4((const TIn*)As + kk * 128 + ty * 4 + 64 * g, a[g]);
#pragma unroll
      for (int h = 0; h < 4; ++h)
        ld4(Bs + kk * 256 + tx * 4 + 64 * h, b[h]);
#pragma unroll
      for (int g = 0; g < 2; ++g)
#pragma unroll
        for (int h = 0; h < 4; ++h)
#pragma unroll
          for (int i = 0; i < 4; ++i)
#pragma unroll
            for (int j = 0; j < 4; ++j)
              acc[g][h][i][j] += a[g][i] * b[h][j];
    }
    __syncthreads();
  }

  // ---- epilogue: bias -> BN -> in-register LIF over t (i) ----------------
#pragma unroll
  for (int h = 0; h < 4; ++h) {
    const int d = bn0 + tx * 4 + 64 * h;
    float bi[4], gg[4], be[4], mu[4], vv[4];
    ld4(&bias[d], bi);
    ld4(&bnp[d], gg);
    ld4(&bnp[C_ + d], be);
    ld4(&bnp[2 * C_ + d], mu);
    ld4(&bnp[3 * C_ + d], vv);
    float inv[4];
#pragma unroll
    for (int j = 0; j < 4; ++j) inv[j] = 1.0f / sqrtf(vv[j] + BN_EPS);
#pragma unroll
    for (int g = 0; g < 2; ++g) {
      const int m = bm_m + ty + 16 * g;
      float sv[4][4];                       // [t][j]
#pragma unroll
      for (int j = 0; j < 4; ++j) {
        float mm = 0.0f;
#pragma unroll
        for (int t = 0; t < 4; ++t) {
          float y = acc[g][h][t][j] + bi[j];
          y = (y - mu[j]) * inv[j] * gg[j] + be[j];
          float m2 = mm + (y - mm) * TAU_INV;
          float s = (m2 - V_TH >= 0.0f) ? 1.0f : 0.0f;
          sv[t][j] = s;
          mm = (s != 0.0f) ? 0.0f : m2;
        }
      }
#pragma unroll
      for (int t = 0; t < 4; ++t)
        st4(&S[((size_t)t * M_ + m) * C_ + d], sv[t]);
    }
  }
}

// ---------------------------------------------------------------------------
// kv_kernel: per (t,b,h) compute kvT_count[e][d] = sum_n K[n][d]*V[n][e].
// Spikes are {0,1} => every count is an integer <= 1024: EXACT in fp32 in any
// summation order (so register blocking / per-wave partials are bit-safe).
// Output: 4 per-wave partials, TRANSPOSED ([w][e][d]) for attn_y's d-major
// inner loop. attn_y sums the partials (integers: exact).
// ---------------------------------------------------------------------------
__global__ __launch_bounds__(256) void kv_kernel(
    const __hip_bfloat16* __restrict__ Kk,
    const __hip_bfloat16* __restrict__ V,
    float* __restrict__ kvpT)
{
  __shared__ __align__(16) __hip_bfloat16 Ks[64 * 64];  // LDS-linear (DMA)
  __shared__ __align__(16) __hip_bfloat16 Vs[64 * 64];
  const int tid  = threadIdx.x;
  const int lane = tid & 63;
  const int w    = __builtin_amdgcn_readfirstlane(tid >> 6);
  const int h = blockIdx.x, b = blockIdx.y, t = blockIdx.z;
  const size_t base = ((size_t)(t * B_ + b) * N_) * C_ + (size_t)h * D_;
  const int d0 = (lane >> 3) * 8;   // 8 d per lane
  const int e0 = (lane & 7) * 8;    // 8 e per lane

  float acc[8][8];
#pragma unroll
  for (int i = 0; i < 8; ++i)
#pragma unroll
    for (int j = 0; j < 8; ++j) acc[i][j] = 0.0f;

  for (int nc = 0; nc < N_; nc += 64) {
    // stage 64-row K,V chunks: 8 dma16 per array, wave w issues 2 of each.
#pragma unroll
    for (int c = 0; c < 2; ++c) {
      const int ins = w * 2 + c;                       // 0..7, 8 rows each
      const int row = ins * 8 + (lane >> 3);
      const int ch  = lane & 7;
      dma16(Kk + base + (size_t)(nc + row) * C_ + ch * 8,
            (void*)(Ks + ins * 512));
      dma16(V  + base + (size_t)(nc + row) * C_ + ch * 8,
            (void*)(Vs + ins * 512));
    }
    __syncthreads();
    // wave w accumulates rows w*16 .. w*16+15 of this chunk (8x8 per lane).
    // a-read: 8 distinct 16B addrs (by lane>>3) -> broadcast groups, 8
    // distinct bank-quads: conflict-free. b-read symmetric (by lane&7).
#pragma unroll
    for (int s = 0; s < 16; ++s) {
      const int nn = w * 16 + s;
      float a[8], bb[8];
      ld8bf(Ks + nn * 64 + d0, a);
      ld8bf(Vs + nn * 64 + e0, bb);
#pragma unroll
      for (int i = 0; i < 8; ++i)
#pragma unroll
        for (int j = 0; j < 8; ++j) acc[i][j] += a[i] * bb[j];
    }
    __syncthreads();
  }

  // store per-wave partial, transposed: kvpT[(t,b,h)][w][e][d]
  float* dst = kvpT + ((((size_t)t * B_ + b) * H_ + h) * 4 + w) * (size_t)(D_ * D_);
#pragma unroll
  for (int j = 0; j < 8; ++j) {
    float tmp[8];
#pragma unroll
    for (int i = 0; i < 8; ++i) tmp[i] = acc[i][j];
    st4(&dst[(e0 + j) * D_ + d0], tmp);
    st4(&dst[(e0 + j) * D_ + d0 + 4], tmp + 4);
  }
}

// ---- expand 2 spike bits (t-pair) to packed bf16 pair ---------------------
// bf16(1.0) == 0x3F80, bf16(0.0) == 0x0000 (same bits __float2bfloat16 emits).
__device__ __forceinline__ unsigned bfpair(unsigned bits, int j, int half) {
  const unsigned p = (bits >> (j * 4 + half * 2)) & 3u;
  return ((p & 1u) ? 0x3F80u : 0u) | ((p & 2u) ? 0x3F800000u : 0u);
}

// ---------------------------------------------------------------------------
// attn_y: per (b,h,n-tile of 128): for each t, y = q @ (kvT/N); LIF across t
// fully in-register; write bf16 spikes DIRECTLY in aT[c][m*4+t] layout.
// Exactness: acc = sum_d q*count is an integer <= 65536 (exact fp32, any
// order); *2^-10 is exact => y bit-identical to reference; LIF expressions
// textually identical to prior rounds.
// Q staging: dma16 with XOR-pre-swizzled GLOBAL source (LDS stays linear for
// DMA); reads apply the same swizzle => 128B-row column reads are <=2-way.
// ---------------------------------------------------------------------------
__global__ __launch_bounds__(256, 2) void attn_y(
    const __hip_bfloat16* __restrict__ Q,
    const float* __restrict__ kvpT,
    __hip_bfloat16* __restrict__ AT)
{
  __shared__ __align__(16) __hip_bfloat16 Qs[128 * 64];  // swizzled chunks
  __shared__ __align__(16) float KVs[64][68];            // kvT[e][d], padded
  const int tid  = threadIdx.x;
  const int lane = tid & 63;
  const int w    = __builtin_amdgcn_readfirstlane(tid >> 6);
  const int n0 = blockIdx.x * 128;
  const int h  = blockIdx.y, b = blockIdx.z;
  const int ng = lane & 15;                  // n = n0 + ng*8 + i
  const int e0 = w * 16 + (lane >> 4) * 4;   // 4 e per thread

  float mem[8][4];
  unsigned svb[8];                           // spike bit (j*4 + t) per n-row
#pragma unroll
  for (int i = 0; i < 8; ++i) {
    svb[i] = 0u;
#pragma unroll
    for (int j = 0; j < 4; ++j) mem[i][j] = 0.0f;
  }

#pragma unroll
  for (int t = 0; t < T_; ++t) {
    if (t) __syncthreads();
    // ---- stage Q tile: 16 dma16, wave w issues 4; chunk pre-swizzled -----
#pragma unroll
    for (int c = 0; c < 4; ++c) {
      const int ins = w * 4 + c;                       // 0..15, 8 rows each
      const int row = ins * 8 + (lane >> 3);
      const int ch  = (lane & 7) ^ (ins & 7);          // XOR swizzle key=row>>3
      dma16(Q + (size_t)(t * M_ + b * N_ + n0 + row) * C_ + h * D_ + ch * 8,
            (void*)(Qs + ins * 512));
    }
    // ---- stage kvT: sum the 4 integer wave-partials (exact) --------------
    const float* kp = kvpT + (((size_t)t * B_ + b) * H_ + h) * 4 * (size_t)(D_ * D_);
#pragma unroll
    for (int g = 0; g < 4; ++g) {
      const int cell = tid * 16 + g * 4;
      const float4 v0 = *(const float4*)(kp + cell);
      const float4 v1 = *(const float4*)(kp + 4096 + cell);
      const float4 v2 = *(const float4*)(kp + 8192 + cell);
      const float4 v3 = *(const float4*)(kp + 12288 + cell);
      float sum[4] = { v0.x + v1.x + v2.x + v3.x, v0.y + v1.y + v2.y + v3.y,
                       v0.z + v1.z + v2.z + v3.z, v0.w + v1.w + v2.w + v3.w };
      st4(&KVs[cell >> 6][cell & 63], sum);
    }
    __syncthreads();

    // ---- y = q @ kvT_count  (8 n x 4 e per thread, d-chunks of 8) --------
    float acc[8][4];
#pragma unroll
    for (int i = 0; i < 8; ++i)
#pragma unroll
      for (int j = 0; j < 4; ++j) acc[i][j] = 0.0f;
#pragma unroll 2
    for (int dc = 0; dc < 8; ++dc) {
      float bb[4][8];
#pragma unroll
      for (int j = 0; j < 4; ++j) {
        ld4(&KVs[e0 + j][dc * 8], bb[j]);          // 4 distinct addrs/wave:
        ld4(&KVs[e0 + j][dc * 8 + 4], bb[j] + 4);  // broadcast, conflict-free
      }
#pragma unroll
      for (int i = 0; i < 8; ++i) {
        float a[8];
        // row n = ng*8+i => swizzle key = (n>>3)&7 = ng&7
        ld8bf(Qs + (ng * 8 + i) * 64 + ((dc ^ (ng & 7)) * 8), a);
#pragma unroll
        for (int dd = 0; dd < 8; ++dd)
#pragma unroll
          for (int j = 0; j < 4; ++j)
            acc[i][j] += a[dd] * bb[j][dd];
      }
    }

    // ---- LIF step for this t (textually identical update) ----------------
#pragma unroll
    for (int i = 0; i < 8; ++i)
#pragma unroll
      for (int j = 0; j < 4; ++j) {
        const float y = acc[i][j] * 0.0009765625f;   // /N_ == *2^-10, exact
        const float m2 = mem[i][j] + (y - mem[i][j]) * TAU_INV;
        const float s = (m2 - V_TH >= 0.0f) ? 1.0f : 0.0f;
        if (s != 0.0f) svb[i] |= 1u << (j * 4 + t);
        mem[i][j] = (s != 0.0f) ? 0.0f : m2;
      }
  }

  // ---- store spikes: aT[c][m*4+t]; per (c): 8 n x 4 t = 64B contiguous ---
  const size_t mbase = ((size_t)b * N_ + n0 + ng * 8) * 4;
#pragma unroll
  for (int j = 0; j < 4; ++j) {
    __hip_bfloat16* dst = AT + (size_t)(h * D_ + e0 + j) * MT_ + mbase;
#pragma unroll
    for (int p = 0; p < 4; ++p) {        // 2 n-rows per uint4
      uint4 u;
      u.x = bfpair(svb[2 * p],     j, 0);
      u.y = bfpair(svb[2 * p],     j, 1);
      u.z = bfpair(svb[2 * p + 1], j, 0);
      u.w = bfpair(svb[2 * p + 1], j, 1);
      *(uint4*)(dst + p * 8) = u;
    }
  }
}

extern "C" void kernel_launch(void* const* d_in, const int* in_sizes, int n_in,
                              void* d_out, int out_size, void* d_ws, size_t ws_size,
                              hipStream_t stream)
{
  const float* x   = (const float*)d_in[0];
  const float* Wq  = (const float*)d_in[1];
  const float* bq  = (const float*)d_in[2];
  const float* Wk  = (const float*)d_in[3];
  const float* bk  = (const float*)d_in[4];
  const float* Wv  = (const float*)d_in[5];
  const float* bv  = (const float*)d_in[6];
  const float* Wp  = (const float*)d_in[7];
  const float* bp  = (const float*)d_in[8];
  const float* bnp = (const float*)d_in[9];   // (4 layers, 4, C)
  float* out = (float*)d_out;

  char* ws = (char*)d_ws;
  float* XT = (float*)ws;  ws += (size_t)K_ * MT_ * sizeof(float);     // 64 MB
  float* Wt = (float*)ws;  ws += (size_t)4 * K_ * C_ * sizeof(float);  //  4 MB
  __hip_bfloat16* q_s = (__hip_bfloat16*)ws; ws += (size_t)MT_ * C_ * 2;
  __hip_bfloat16* k_s = (__hip_bfloat16*)ws; ws += (size_t)MT_ * C_ * 2;
  __hip_bfloat16* v_s = (__hip_bfloat16*)ws; ws += (size_t)MT_ * C_ * 2;
  // XT is dead after the qkv GEMMs: reuse it for the attn outputs.
  // (aT must NOT alias q_s: attn_y reads q_s while writing aT.)
  __hip_bfloat16* aT = (__hip_bfloat16*)XT;                       // 32 MB
  float* kvpT = (float*)((char*)XT + (size_t)32 * 1024 * 1024);   // 16.8 MB

  // ---- one-time per-launch transposes ------------------------------------
  WPtrs wp; wp.W[0] = Wq; wp.W[1] = Wk; wp.W[2] = Wv; wp.W[3] = Wp;
  transpose_w<<<dim3(K_ / 32, C_ / 32, 4), dim3(32, 8), 0, stream>>>(wp, Wt);
  transpose_x<<<dim3(K_ / 32, M_ / 32), 256, 0, stream>>>(x, XT);

  // ---- fused q,k,v GEMM+BN+LIF (one dispatch, z = weight) ----------------
  GArgs<float, __hip_bfloat16> qa;
  qa.AT = XT;
  qa.Wt[0] = Wt; qa.Wt[1] = Wt + (size_t)K_ * C_; qa.Wt[2] = Wt + (size_t)2 * K_ * C_;
  qa.bias[0] = bq; qa.bias[1] = bk; qa.bias[2] = bv;
  qa.bn[0] = bnp + 0 * 4 * C_;
  qa.bn[1] = bnp + 1 * 4 * C_;
  qa.bn[2] = bnp + 2 * 4 * C_;
  qa.S[0] = q_s; qa.S[1] = k_s; qa.S[2] = v_s;
  gemm_lif<float, __hip_bfloat16>
      <<<dim3(C_ / 256, M_ / 32, 3), 256, 0, stream>>>(qa);

  // ---- attention (exact integer arithmetic) ------------------------------
  kv_kernel<<<dim3(H_, B_, T_), 256, 0, stream>>>(k_s, v_s, kvpT);
  attn_y<<<dim3(N_ / 128, H_, B_), 256, 0, stream>>>(q_s, kvpT, aT);

  // ---- proj GEMM+BN+LIF -> out (fp32 spikes) -----------------------------
  GArgs<__hip_bfloat16, float> pa;
  pa.AT = aT;
  pa.Wt[0] = Wt + (size_t)3 * K_ * C_;
  pa.bias[0] = bp;
  pa.bn[0] = bnp + 3 * 4 * C_;
  pa.S[0] = out;
  gemm_lif<__hip_bfloat16, float>
      <<<dim3(C_ / 256, M_ / 32, 1), 256, 0, stream>>>(pa);
}

// Round 2
// 949.163 us; speedup vs baseline: 1.1581x; 1.1581x over previous
//
#include <hip/hip_runtime.h>
#include <hip/hip_bf16.h>

// Problem constants (fixed by setup_inputs)
constexpr int T_ = 4, B_ = 8, N_ = 1024, C_ = 512, H_ = 8, D_ = 64;
constexpr int M_ = 8192;             // rows per timestep
constexpr int MT_ = 32768;           // T*M
constexpr int K_ = 512;

#define TAU_INV 0.5f
#define V_TH    1.0f
#define BN_EPS  1e-5f

typedef float v2f __attribute__((ext_vector_type(2)));
typedef float v4f __attribute__((ext_vector_type(4)));

// ---- load 4 consecutive elements as float ---------------------------------
__device__ __forceinline__ void ld4(const float* p, float* d) {
  const float4 v = *(const float4*)p;
  d[0] = v.x; d[1] = v.y; d[2] = v.z; d[3] = v.w;
}
__device__ __forceinline__ void ld4(const __hip_bfloat16* p, float* d) {
  const ushort4 u = *(const ushort4*)p;
  d[0] = __bfloat162float(*(const __hip_bfloat16*)&u.x);
  d[1] = __bfloat162float(*(const __hip_bfloat16*)&u.y);
  d[2] = __bfloat162float(*(const __hip_bfloat16*)&u.z);
  d[3] = __bfloat162float(*(const __hip_bfloat16*)&u.w);
}
// ---- load 4 consecutive elements as two fp32 pairs ------------------------
__device__ __forceinline__ void ld4p(const float* p, v2f& lo, v2f& hi) {
  union { v4f v; v2f h[2]; } u;
  u.v = *(const v4f*)p;
  lo = u.h[0]; hi = u.h[1];
}
__device__ __forceinline__ void ld4p(const __hip_bfloat16* p, v2f& lo, v2f& hi) {
  const ushort4 u = *(const ushort4*)p;
  lo[0] = __bfloat162float(*(const __hip_bfloat16*)&u.x);
  lo[1] = __bfloat162float(*(const __hip_bfloat16*)&u.y);
  hi[0] = __bfloat162float(*(const __hip_bfloat16*)&u.z);
  hi[1] = __bfloat162float(*(const __hip_bfloat16*)&u.w);
}
// ---- load 8 consecutive bf16 as float -------------------------------------
__device__ __forceinline__ void ld8bf(const __hip_bfloat16* p, float* d) {
  union { uint4 u; ushort s[8]; } q;
  q.u = *(const uint4*)p;
#pragma unroll
  for (int j = 0; j < 8; ++j)
    d[j] = __bfloat162float(*(const __hip_bfloat16*)&q.s[j]);
}
// ---- store 4 consecutive values -------------------------------------------
__device__ __forceinline__ void st4(__hip_bfloat16* p, const float* s) {
  ushort4 u;
  *(__hip_bfloat16*)&u.x = __float2bfloat16(s[0]);
  *(__hip_bfloat16*)&u.y = __float2bfloat16(s[1]);
  *(__hip_bfloat16*)&u.z = __float2bfloat16(s[2]);
  *(__hip_bfloat16*)&u.w = __float2bfloat16(s[3]);
  *(ushort4*)p = u;
}
__device__ __forceinline__ void st4(float* p, const float* s) {
  *(float4*)p = make_float4(s[0], s[1], s[2], s[3]);
}

// ---- packed fp32 FMA (VOP3P). Each half is an IEEE fp32 FMA, identical to
// v_fma_f32 -> per-element accumulation chains are bit-identical to the
// scalar version. op_sel broadcasts one half of `a` to both lanes (no movs).
// pk_fma_lo: acc.lo += a.lo*b.lo ; acc.hi += a.lo*b.hi
// pk_fma_hi: acc.lo += a.hi*b.lo ; acc.hi += a.hi*b.hi
__device__ __forceinline__ void pk_fma_lo(v2f& acc, const v2f a, const v2f b) {
  asm("v_pk_fma_f32 %0, %1, %2, %0 op_sel:[0,0,0] op_sel_hi:[0,1,1]"
      : "+v"(acc) : "v"(a), "v"(b));
}
__device__ __forceinline__ void pk_fma_hi(v2f& acc, const v2f a, const v2f b) {
  asm("v_pk_fma_f32 %0, %1, %2, %0 op_sel:[1,0,0] op_sel_hi:[1,1,1]"
      : "+v"(acc) : "v"(a), "v"(b));
}

// ---- async global->LDS, 16B per lane (HW scatters lane*16 from wave base) --
__device__ __forceinline__ void dma16(const void* g, void* l) {
  __builtin_amdgcn_global_load_lds(
      (const __attribute__((address_space(1))) unsigned int*)g,
      (__attribute__((address_space(3))) unsigned int*)l, 16, 0, 0);
}

// ---------------------------------------------------------------------------
// W transpose: Wt[w][k][d] = W[w][d][k]  (k-major rows for DMA staging).
// ---------------------------------------------------------------------------
struct WPtrs { const float* W[4]; };

__global__ __launch_bounds__(256) void transpose_w(WPtrs wp, float* __restrict__ Wt)
{
  __shared__ float tile[32][33];
  const int w = blockIdx.z;
  const float* __restrict__ W = wp.W[w];
  float* __restrict__ dst = Wt + (size_t)w * K_ * C_;
  const int k0 = blockIdx.x * 32, d0 = blockIdx.y * 32;
  const int tx = threadIdx.x, ty = threadIdx.y;   // 32 x 8
#pragma unroll
  for (int i = 0; i < 32; i += 8)
    tile[ty + i][tx] = W[(size_t)(d0 + ty + i) * K_ + k0 + tx];
  __syncthreads();
#pragma unroll
  for (int i = 0; i < 32; i += 8)
    dst[(size_t)(k0 + ty + i) * C_ + d0 + tx] = tile[tx][ty + i];
}

// ---------------------------------------------------------------------------
// x transpose: XT[k][m*4 + t] = x[t][m][k]   (k-major, t-interleaved rows).
// ---------------------------------------------------------------------------
__global__ __launch_bounds__(256) void transpose_x(
    const float* __restrict__ x, float* __restrict__ XT)
{
  __shared__ float tile[32][132];
  const int bk = blockIdx.x * 32, bm = blockIdx.y * 32;
  const int tx = threadIdx.x & 31, ty = threadIdx.x >> 5;   // 32 x 8
#pragma unroll
  for (int t = 0; t < T_; ++t)
#pragma unroll
    for (int i = 0; i < 4; ++i) {
      const int m = ty + 8 * i;
      tile[tx][m * 4 + t] = x[((size_t)t * M_ + bm + m) * K_ + bk + tx];
    }
  __syncthreads();
  const int k = threadIdx.x >> 3, q = threadIdx.x & 7;
#pragma unroll
  for (int u = 0; u < 4; ++u)
    st4(&XT[(size_t)(bk + k) * MT_ + bm * 4 + q * 16 + u * 4],
        &tile[k][q * 16 + u * 4]);
}

// ---------------------------------------------------------------------------
// Fused GEMM (+bias +BN +in-register multi-step LIF) -> spike tensor (T,M,C).
// BIT-EXACTNESS CONTRACT: each output's k-summation is a single fp32
// accumulator over k = 0..511 STRICTLY ASCENDING, one fused FMA per step.
// v_pk_fma_f32 halves FMA issue slots; per-element rounding/order identical.
// Epilogue expressions textually identical to all prior passing rounds.
// ---------------------------------------------------------------------------
template <typename TIn, typename TOut>
struct GArgs {
  const TIn* AT;             // [K][MT] t-interleaved k-major input
  const float* Wt[3];        // [K][C]
  const float* bias[3];
  const float* bn[3];
  TOut* S[3];                // (T, M, C) spikes
};

template <typename TIn, typename TOut>
__global__ __launch_bounds__(256, 2) void gemm_lif(GArgs<TIn, TOut> args)
{
  constexpr int BK = 32;
  constexpr bool BF = (sizeof(TIn) == 2);
  __shared__ __align__(16) TIn  As[BK * 128];
  __shared__ __align__(16) float Bs[BK * 256];

  const int z = blockIdx.z;
  const TIn*   __restrict__ AT   = args.AT;
  const float* __restrict__ Wt   = args.Wt[z];
  const float* __restrict__ bias = args.bias[z];
  const float* __restrict__ bnp  = args.bn[z];
  TOut*        __restrict__ S    = args.S[z];

  const int tid  = threadIdx.x;
  const int lane = tid & 63;
  const int wave = __builtin_amdgcn_readfirstlane(tid >> 6);
  const int tx = tid & 15, ty = tid >> 4;
  const int bm_m = blockIdx.y * 32;       // m-tile base
  const int bm4  = bm_m * 4;              // word base within a k-row of AT
  const int bn0  = blockIdx.x * 256;

  // acc[g][h][i][jp] : v2f pair covers cols (2jp, 2jp+1); i == t
  v2f acc[2][4][4][2];
#pragma unroll
  for (int g = 0; g < 2; ++g)
#pragma unroll
    for (int h = 0; h < 4; ++h)
#pragma unroll
      for (int i = 0; i < 4; ++i)
#pragma unroll
        for (int jp = 0; jp < 2; ++jp) { acc[g][h][i][jp][0] = 0.0f; acc[g][h][i][jp][1] = 0.0f; }

  for (int k0 = 0; k0 < K_; k0 += BK) {
    // ---- DMA-stage A tile (BK x 128 elems) -------------------------------
    if constexpr (!BF) {
#pragma unroll
      for (int c = 0; c < 4; ++c) {
        const int ins = wave * 4 + c;                 // 0..15, 2 kk-rows each
        const int kk = ins * 2 + (lane >> 5);
        dma16(AT + (size_t)(k0 + kk) * MT_ + bm4 + (lane & 31) * 4,
              (void*)((float*)As + ins * 256));
      }
    } else {
#pragma unroll
      for (int c = 0; c < 2; ++c) {
        const int ins = wave * 2 + c;                 // 0..7, 4 kk-rows each
        const int kk = ins * 4 + (lane >> 4);
        dma16(AT + (size_t)(k0 + kk) * MT_ + bm4 + (lane & 15) * 8,
              (void*)((TIn*)As + ins * 512));
      }
    }
    // ---- DMA-stage B tile (BK x 256 floats) ------------------------------
#pragma unroll
    for (int c = 0; c < 8; ++c) {
      const int ins = wave * 8 + c;                   // 0..31, 1 kk-row each
      dma16(Wt + (size_t)(k0 + ins) * C_ + bn0 + lane * 4,
            (void*)(Bs + ins * 256));
    }
    __syncthreads();                                  // drains vmcnt

    // ---- hot loop: k strictly ascending, packed over j pairs -------------
#pragma unroll
    for (int kk = 0; kk < BK; ++kk) {
      v2f aL[2], aH[2], bL[4], bH[4];
#pragma unroll
      for (int g = 0; g < 2; ++g)
        ld4p((const TIn*)As + kk * 128 + ty * 4 + 64 * g, aL[g], aH[g]);
#pragma unroll
      for (int h = 0; h < 4; ++h)
        ld4p(Bs + kk * 256 + tx * 4 + 64 * h, bL[h], bH[h]);
#pragma unroll
      for (int g = 0; g < 2; ++g)
#pragma unroll
        for (int h = 0; h < 4; ++h) {
          pk_fma_lo(acc[g][h][0][0], aL[g], bL[h]);   // i=0 (a.lo)
          pk_fma_lo(acc[g][h][0][1], aL[g], bH[h]);
          pk_fma_hi(acc[g][h][1][0], aL[g], bL[h]);   // i=1 (a.hi)
          pk_fma_hi(acc[g][h][1][1], aL[g], bH[h]);
          pk_fma_lo(acc[g][h][2][0], aH[g], bL[h]);   // i=2
          pk_fma_lo(acc[g][h][2][1], aH[g], bH[h]);
          pk_fma_hi(acc[g][h][3][0], aH[g], bL[h]);   // i=3
          pk_fma_hi(acc[g][h][3][1], aH[g], bH[h]);
        }
    }
    __syncthreads();
  }

  // ---- epilogue: bias -> BN -> in-register LIF over t (i) ----------------
#pragma unroll
  for (int h = 0; h < 4; ++h) {
    const int d = bn0 + tx * 4 + 64 * h;
    float bi[4], gg[4], be[4], mu[4], vv[4];
    ld4(&bias[d], bi);
    ld4(&bnp[d], gg);
    ld4(&bnp[C_ + d], be);
    ld4(&bnp[2 * C_ + d], mu);
    ld4(&bnp[3 * C_ + d], vv);
    float inv[4];
#pragma unroll
    for (int j = 0; j < 4; ++j) inv[j] = 1.0f / sqrtf(vv[j] + BN_EPS);
#pragma unroll
    for (int g = 0; g < 2; ++g) {
      const int m = bm_m + ty + 16 * g;
      float sv[4][4];                       // [t][j]
#pragma unroll
      for (int j = 0; j < 4; ++j) {
        float mm = 0.0f;
#pragma unroll
        for (int t = 0; t < 4; ++t) {
          float y = acc[g][h][t][j >> 1][j & 1] + bi[j];
          y = (y - mu[j]) * inv[j] * gg[j] + be[j];
          float m2 = mm + (y - mm) * TAU_INV;
          float s = (m2 - V_TH >= 0.0f) ? 1.0f : 0.0f;
          sv[t][j] = s;
          mm = (s != 0.0f) ? 0.0f : m2;
        }
      }
#pragma unroll
      for (int t = 0; t < 4; ++t)
        st4(&S[((size_t)t * M_ + m) * C_ + d], sv[t]);
    }
  }
}

// ---------------------------------------------------------------------------
// kv_kernel: per (t,b,h) compute kvT_count[e][d] = sum_n K[n][d]*V[n][e].
// Spikes are {0,1} => every count is an integer <= 1024: EXACT in fp32 in any
// summation order (so register blocking / per-wave partials are bit-safe).
// ---------------------------------------------------------------------------
__global__ __launch_bounds__(256) void kv_kernel(
    const __hip_bfloat16* __restrict__ Kk,
    const __hip_bfloat16* __restrict__ V,
    float* __restrict__ kvpT)
{
  __shared__ __align__(16) __hip_bfloat16 Ks[64 * 64];  // LDS-linear (DMA)
  __shared__ __align__(16) __hip_bfloat16 Vs[64 * 64];
  const int tid  = threadIdx.x;
  const int lane = tid & 63;
  const int w    = __builtin_amdgcn_readfirstlane(tid >> 6);
  const int h = blockIdx.x, b = blockIdx.y, t = blockIdx.z;
  const size_t base = ((size_t)(t * B_ + b) * N_) * C_ + (size_t)h * D_;
  const int d0 = (lane >> 3) * 8;   // 8 d per lane
  const int e0 = (lane & 7) * 8;    // 8 e per lane

  float acc[8][8];
#pragma unroll
  for (int i = 0; i < 8; ++i)
#pragma unroll
    for (int j = 0; j < 8; ++j) acc[i][j] = 0.0f;

  for (int nc = 0; nc < N_; nc += 64) {
#pragma unroll
    for (int c = 0; c < 2; ++c) {
      const int ins = w * 2 + c;                       // 0..7, 8 rows each
      const int row = ins * 8 + (lane >> 3);
      const int ch  = lane & 7;
      dma16(Kk + base + (size_t)(nc + row) * C_ + ch * 8,
            (void*)(Ks + ins * 512));
      dma16(V  + base + (size_t)(nc + row) * C_ + ch * 8,
            (void*)(Vs + ins * 512));
    }
    __syncthreads();
#pragma unroll
    for (int s = 0; s < 16; ++s) {
      const int nn = w * 16 + s;
      float a[8], bb[8];
      ld8bf(Ks + nn * 64 + d0, a);
      ld8bf(Vs + nn * 64 + e0, bb);
#pragma unroll
      for (int i = 0; i < 8; ++i)
#pragma unroll
        for (int j = 0; j < 8; ++j) acc[i][j] += a[i] * bb[j];
    }
    __syncthreads();
  }

  // store per-wave partial, transposed: kvpT[(t,b,h)][w][e][d]
  float* dst = kvpT + ((((size_t)t * B_ + b) * H_ + h) * 4 + w) * (size_t)(D_ * D_);
#pragma unroll
  for (int j = 0; j < 8; ++j) {
    float tmp[8];
#pragma unroll
    for (int i = 0; i < 8; ++i) tmp[i] = acc[i][j];
    st4(&dst[(e0 + j) * D_ + d0], tmp);
    st4(&dst[(e0 + j) * D_ + d0 + 4], tmp + 4);
  }
}

// ---- expand 2 spike bits (t-pair) to packed bf16 pair ---------------------
__device__ __forceinline__ unsigned bfpair(unsigned bits, int j, int half) {
  const unsigned p = (bits >> (j * 4 + half * 2)) & 3u;
  return ((p & 1u) ? 0x3F80u : 0u) | ((p & 2u) ? 0x3F800000u : 0u);
}

// ---------------------------------------------------------------------------
// attn_y: per (b,h,n-tile of 128): for each t, y = q @ (kvT/N); LIF across t
// fully in-register; write bf16 spikes DIRECTLY in aT[c][m*4+t] layout.
// Exactness: integer counts -> any order is exact fp32; *2^-10 exact.
// ---------------------------------------------------------------------------
__global__ __launch_bounds__(256, 2) void attn_y(
    const __hip_bfloat16* __restrict__ Q,
    const float* __restrict__ kvpT,
    __hip_bfloat16* __restrict__ AT)
{
  __shared__ __align__(16) __hip_bfloat16 Qs[128 * 64];  // swizzled chunks
  __shared__ __align__(16) float KVs[64][68];            // kvT[e][d], padded
  const int tid  = threadIdx.x;
  const int lane = tid & 63;
  const int w    = __builtin_amdgcn_readfirstlane(tid >> 6);
  const int n0 = blockIdx.x * 128;
  const int h  = blockIdx.y, b = blockIdx.z;
  const int ng = lane & 15;                  // n = n0 + ng*8 + i
  const int e0 = w * 16 + (lane >> 4) * 4;   // 4 e per thread

  float mem[8][4];
  unsigned svb[8];                           // spike bit (j*4 + t) per n-row
#pragma unroll
  for (int i = 0; i < 8; ++i) {
    svb[i] = 0u;
#pragma unroll
    for (int j = 0; j < 4; ++j) mem[i][j] = 0.0f;
  }

#pragma unroll
  for (int t = 0; t < T_; ++t) {
    if (t) __syncthreads();
#pragma unroll
    for (int c = 0; c < 4; ++c) {
      const int ins = w * 4 + c;                       // 0..15, 8 rows each
      const int row = ins * 8 + (lane >> 3);
      const int ch  = (lane & 7) ^ (ins & 7);          // XOR swizzle key=row>>3
      dma16(Q + (size_t)(t * M_ + b * N_ + n0 + row) * C_ + h * D_ + ch * 8,
            (void*)(Qs + ins * 512));
    }
    const float* kp = kvpT + (((size_t)t * B_ + b) * H_ + h) * 4 * (size_t)(D_ * D_);
#pragma unroll
    for (int g = 0; g < 4; ++g) {
      const int cell = tid * 16 + g * 4;
      const float4 v0 = *(const float4*)(kp + cell);
      const float4 v1 = *(const float4*)(kp + 4096 + cell);
      const float4 v2 = *(const float4*)(kp + 8192 + cell);
      const float4 v3 = *(const float4*)(kp + 12288 + cell);
      float sum[4] = { v0.x + v1.x + v2.x + v3.x, v0.y + v1.y + v2.y + v3.y,
                       v0.z + v1.z + v2.z + v3.z, v0.w + v1.w + v2.w + v3.w };
      st4(&KVs[cell >> 6][cell & 63], sum);
    }
    __syncthreads();

    float acc[8][4];
#pragma unroll
    for (int i = 0; i < 8; ++i)
#pragma unroll
      for (int j = 0; j < 4; ++j) acc[i][j] = 0.0f;
#pragma unroll 2
    for (int dc = 0; dc < 8; ++dc) {
      float bb[4][8];
#pragma unroll
      for (int j = 0; j < 4; ++j) {
        ld4(&KVs[e0 + j][dc * 8], bb[j]);
        ld4(&KVs[e0 + j][dc * 8 + 4], bb[j] + 4);
      }
#pragma unroll
      for (int i = 0; i < 8; ++i) {
        float a[8];
        ld8bf(Qs + (ng * 8 + i) * 64 + ((dc ^ (ng & 7)) * 8), a);
#pragma unroll
        for (int dd = 0; dd < 8; ++dd)
#pragma unroll
          for (int j = 0; j < 4; ++j)
            acc[i][j] += a[dd] * bb[j][dd];
      }
    }

#pragma unroll
    for (int i = 0; i < 8; ++i)
#pragma unroll
      for (int j = 0; j < 4; ++j) {
        const float y = acc[i][j] * 0.0009765625f;   // /N_ == *2^-10, exact
        const float m2 = mem[i][j] + (y - mem[i][j]) * TAU_INV;
        const float s = (m2 - V_TH >= 0.0f) ? 1.0f : 0.0f;
        if (s != 0.0f) svb[i] |= 1u << (j * 4 + t);
        mem[i][j] = (s != 0.0f) ? 0.0f : m2;
      }
  }

  const size_t mbase = ((size_t)b * N_ + n0 + ng * 8) * 4;
#pragma unroll
  for (int j = 0; j < 4; ++j) {
    __hip_bfloat16* dst = AT + (size_t)(h * D_ + e0 + j) * MT_ + mbase;
#pragma unroll
    for (int p = 0; p < 4; ++p) {
      uint4 u;
      u.x = bfpair(svb[2 * p],     j, 0);
      u.y = bfpair(svb[2 * p],     j, 1);
      u.z = bfpair(svb[2 * p + 1], j, 0);
      u.w = bfpair(svb[2 * p + 1], j, 1);
      *(uint4*)(dst + p * 8) = u;
    }
  }
}

extern "C" void kernel_launch(void* const* d_in, const int* in_sizes, int n_in,
                              void* d_out, int out_size, void* d_ws, size_t ws_size,
                              hipStream_t stream)
{
  const float* x   = (const float*)d_in[0];
  const float* Wq  = (const float*)d_in[1];
  const float* bq  = (const float*)d_in[2];
  const float* Wk  = (const float*)d_in[3];
  const float* bk  = (const float*)d_in[4];
  const float* Wv  = (const float*)d_in[5];
  const float* bv  = (const float*)d_in[6];
  const float* Wp  = (const float*)d_in[7];
  const float* bp  = (const float*)d_in[8];
  const float* bnp = (const float*)d_in[9];   // (4 layers, 4, C)
  float* out = (float*)d_out;

  char* ws = (char*)d_ws;
  float* XT = (float*)ws;  ws += (size_t)K_ * MT_ * sizeof(float);     // 64 MB
  float* Wt = (float*)ws;  ws += (size_t)4 * K_ * C_ * sizeof(float);  //  4 MB
  __hip_bfloat16* q_s = (__hip_bfloat16*)ws; ws += (size_t)MT_ * C_ * 2;
  __hip_bfloat16* k_s = (__hip_bfloat16*)ws; ws += (size_t)MT_ * C_ * 2;
  __hip_bfloat16* v_s = (__hip_bfloat16*)ws; ws += (size_t)MT_ * C_ * 2;
  __hip_bfloat16* aT = (__hip_bfloat16*)XT;                       // 32 MB
  float* kvpT = (float*)((char*)XT + (size_t)32 * 1024 * 1024);   // 16.8 MB

  WPtrs wp; wp.W[0] = Wq; wp.W[1] = Wk; wp.W[2] = Wv; wp.W[3] = Wp;
  transpose_w<<<dim3(K_ / 32, C_ / 32, 4), dim3(32, 8), 0, stream>>>(wp, Wt);
  transpose_x<<<dim3(K_ / 32, M_ / 32), 256, 0, stream>>>(x, XT);

  GArgs<float, __hip_bfloat16> qa;
  qa.AT = XT;
  qa.Wt[0] = Wt; qa.Wt[1] = Wt + (size_t)K_ * C_; qa.Wt[2] = Wt + (size_t)2 * K_ * C_;
  qa.bias[0] = bq; qa.bias[1] = bk; qa.bias[2] = bv;
  qa.bn[0] = bnp + 0 * 4 * C_;
  qa.bn[1] = bnp + 1 * 4 * C_;
  qa.bn[2] = bnp + 2 * 4 * C_;
  qa.S[0] = q_s; qa.S[1] = k_s; qa.S[2] = v_s;
  gemm_lif<float, __hip_bfloat16>
      <<<dim3(C_ / 256, M_ / 32, 3), 256, 0, stream>>>(qa);

  kv_kernel<<<dim3(H_, B_, T_), 256, 0, stream>>>(k_s, v_s, kvpT);
  attn_y<<<dim3(N_ / 128, H_, B_), 256, 0, stream>>>(q_s, kvpT, aT);

  GArgs<__hip_bfloat16, float> pa;
  pa.AT = aT;
  pa.Wt[0] = Wt + (size_t)3 * K_ * C_;
  pa.bias[0] = bp;
  pa.bn[0] = bnp + 3 * 4 * C_;
  pa.S[0] = out;
  gemm_lif<__hip_bfloat16, float>
      <<<dim3(C_ / 256, M_ / 32, 1), 256, 0, stream>>>(pa);
}